// Round 8
// baseline (282.534 us; speedup 1.0000x reference)
//
#include <hip/hip_runtime.h>
#include <stdint.h>

static constexpr int kN = 128;
static constexpr int kTri = (kN * (kN - 1)) / 2;   // 8128 (BT scratch indexing)
static constexpr int kTriD = (kN * (kN + 1)) / 2;  // 8256 cells incl. diagonal
static constexpr int kThreads = 512;               // 8 waves: halves reduction+overhead issue
static constexpr float kNeg = -9999.0f;
static constexpr float kThresh = -9000.0f;
static constexpr float kArcBonus = 5.0f;
static constexpr int kDynLds = kTriD * 16;  // 132,096 B (one float4 quad per cell)
static constexpr int kCMax = 16;            // max row-cache slots per lane

__device__ __forceinline__ int rowBase(int i) { return (i * (2 * kN - 1 - i)) / 2; }
__device__ __forceinline__ int colBaseD(int c) { return (c * (c + 1)) / 2; }  // cells (r<=c, c)

// LDS-only workgroup barrier: orders LDS without draining vmcnt (wsBT stores
// and vL/vR prefetch loads stay in flight across steps).
__device__ __forceinline__ void ldsBarrier() {
    asm volatile("s_waitcnt lgkmcnt(0)\n\ts_barrier" ::: "memory");
}

// DPP cross-lane reduce helpers -- pure VALU, never touch the LDS pipe.
// 0xB1 = quad_perm swap-1 (xor1), 0x4E = quad_perm swap-2 (xor2),
// 0x141 = row_half_mirror (mirror within 8 lanes).
template <int CTRL>
__device__ __forceinline__ float dppMax(float x) {
    const int y = __builtin_amdgcn_update_dpp(__float_as_int(x), __float_as_int(x),
                                              CTRL, 0xF, 0xF, true);
    return fmaxf(x, __int_as_float(y));
}
template <int CTRL>
__device__ __forceinline__ int dppMinI(int x) {
    const int y = __builtin_amdgcn_update_dpp(x, x, CTRL, 0xF, 0xF, true);
    return (y < x) ? y : x;
}

// Quad per cell: {x=s00, y=s11, z=s01, w=s10}, col-major incl. diagonal (diag=0).
__device__ __forceinline__ float4 writeCell(float4* __restrict__ Q4,
                                            uint32_t* __restrict__ wsBT,
                                            int qjb, int i, int wsIdx, int k,
                                            float gb, int ib, float vLc, float vRc,
                                            float v01, int i01, float v11, int i11) {
    const float v00 = (gb + vLc) + kArcBonus;
    const float v10 = (gb + vRc) + kArcBonus;
    const float new10 = (v10 > kThresh) ? v10 : kNeg;
    if (new10 > v11) { v11 = new10; i11 = k; }  // q=j candidate; strict > keeps earlier q
    float4 w = make_float4(kNeg, kNeg, kNeg, kNeg);
    uint32_t p = 0;
    if (v00 > kThresh) { w.x = v00; p |= (uint32_t)(i + ib); }
    if (v01 > kThresh) { w.z = v01; p |= (uint32_t)(i + i01) << 8; }
    if (v10 > kThresh) { w.w = v10; p |= (uint32_t)(i + ib) << 16; }
    if (v11 > kThresh) { w.y = v11; p |= (uint32_t)(i + i11) << 24; }
    Q4[qjb + i] = w;      // one ds_write_b128
    wsBT[wsIdx] = p;      // lone global store; drained at the final __syncthreads
    return w;
}

// Serial step (k<=16), k COMPILE-TIME (caller unrolled): one thread per cell,
// i = tid fixed, all row operands are this thread's own prior outputs mirrored
// in sr[] registers. Incremental j/qjb/pL/pR (no per-step remap).
__device__ __forceinline__ void doStepSerialReg(int k, int i,
                                                float4* __restrict__ Q4,
                                                uint32_t* __restrict__ wsBT,
                                                int& j, int& qjb, int rbi,
                                                const float*& pL, const float*& pR,
                                                float& vL, float& vR,
                                                float (&sr11)[17], float (&sr01)[17],
                                                float (&sr10)[17]) {
    const bool act = i < kN - k;
    const float vLc = vL, vRc = vR;
    const int qjbc = qjb;
    float bmax = -3.0e38f, v01 = -3.0e38f, v11 = -3.0e38f;
    int ib = 0, i01 = 0, i11 = 0x7FFFFFFF;
    if (act) {
        float4 cur = Q4[qjbc + i + 1];  // quad(i+1, j); diagonal zeros when k==1
        bmax = cur.z; ib = 0;           // base(0) = 0 + s01[i+1][j]
        const float p00 = (cur.z + vLc) + kArcBonus;
        v01 = (p00 > kThresh) ? p00 : kNeg; i01 = 0;  // part00 seed
#pragma unroll
        for (int m = 1; m < 16; ++m) {
            if (m < k) {  // compile-time when k is constant-folded
                const float4 nxt = Q4[qjbc + i + m + 1];  // quad(q+1, j)
                const float base = sr11[m] + nxt.z;       // s11[i][q] + s01[q+1][j]
                const float p01v = sr01[m] + cur.x;       // s01[i][q] + s00[q][j]
                const float p11v = sr10[m] + cur.y;       // s10[i][q] + s11[q][j]
                if (base > bmax) { bmax = base; ib = m; }  // strict > keeps earliest m
                if (p01v > v01) { v01 = p01v; i01 = m; }
                if (p11v > v11) { v11 = p11v; i11 = m; }
                cur = nxt;
            }
        }
    }
    // Incremental prefetch of next step's operands (overlaps write + barrier).
    if (k < 16) {
        const bool nact = i < kN - (k + 1);
        qjb += j + 1; ++j; pL += kN; ++pR;
        vL = nact ? *pL : 0.f;
        vR = nact ? *pR : 0.f;
    }
    if (act) {
        const float4 w = writeCell(Q4, wsBT, qjbc, i, rbi + k - 1, k,
                                   bmax, ib, vLc, vRc, v01, i01, v11, i11);
        sr11[k] = w.y; sr01[k] = w.z; sr10[k] = w.w;  // constant index (k unrolled)
    }
}

// ---- Chunked phases: register row-cache + fw forwarding (verified R4) ----
template <int LP, int C>
__device__ __forceinline__ void preloadRow(int k0, int tid,
                                           const float4* __restrict__ Q4,
                                           float (&r11)[kCMax], float (&r01)[kCMax],
                                           float (&r10)[kCMax]) {
    const int i = tid >> LP;
    const int l = tid & ((1 << LP) - 1);
    const int mlo = l * C;
    const int mstart = mlo ? mlo : 1;
    const bool act = i < (kN - k0);
#pragma unroll
    for (int c = 0; c < C; ++c) {
        const int m = mstart + c;
        if (act && (m < mlo + C) && (m <= k0 - 1)) {
            const float4 d = Q4[colBaseD(i + m) + i];  // quad(i, i+m), immutable
            r11[c] = d.y; r01[c] = d.z; r10[c] = d.w;
        }
    }
    // Slots with m > k0-1 stay stale: first read at step k=m+1 substitutes fw.
}

template <int LP, int C>
__device__ __forceinline__ void fwInit(int k0, int tid,
                                       const float (&r11)[kCMax], const float (&r01)[kCMax],
                                       const float (&r10)[kCMax],
                                       float& fw11, float& fw01, float& fw10) {
    const int l = tid & ((1 << LP) - 1);
    const int mlo = l * C;
    const int mstart = mlo ? mlo : 1;
#pragma unroll
    for (int c = 0; c < C; ++c) {
        if (mstart + c == k0 - 1) { fw11 = r11[c]; fw01 = r01[c]; fw10 = r10[c]; }
    }
}

// One DP step for a LIVE wave (first group alive; dead groups masked by act).
template <int LP, int C>
__device__ __forceinline__ void doStepC(int k, int i, int l,
                                        float4* __restrict__ Q4,
                                        uint32_t* __restrict__ wsBT,
                                        int& j, int& qjb, int rbi,
                                        const float*& pL, const float*& pR,
                                        float& vL, float& vR,
                                        float (&r11)[kCMax], float (&r01)[kCMax],
                                        float (&r10)[kCMax],
                                        float& fw11, float& fw01, float& fw10) {
    constexpr int P = 1 << LP;
    static_assert(P <= 8, "reductions are 2-3 DPP levels");
    const bool act = i < kN - k;
    const float vLc = vL, vRc = vR;  // prefetch below overwrites vL/vR
    const int mlo = l * C;
    const int mstart = mlo ? mlo : 1;
    const int mhi = (mlo + C < k) ? (mlo + C) : k;
    const int qjbc = qjb;

    float bmax = -3.0e38f, v01 = -3.0e38f, v11 = -3.0e38f;
    int ib = 0x7FFFFFFF, i01 = 0x7FFFFFFF, i11 = 0x7FFFFFFF;

    const int mf = k - 1;
    const bool lact = act && (mstart < mhi);
    float4 cur = make_float4(0.f, 0.f, 0.f, 0.f);
    if (lact) cur = Q4[qjbc + i + mstart];  // column seed quad(i+mstart, j)
    if (act && mlo == 0) {
        bmax = cur.z; ib = 0;  // base(0) = 0 + s01[i+1][j]
        const float p00 = (cur.z + vLc) + kArcBonus;
        v01 = (p00 > kThresh) ? p00 : kNeg; i01 = 0;  // part00 seed
    }
#pragma unroll
    for (int c = 0; c < C; ++c) {
        const int m = mstart + c;
        // Row operands: registers; fresh slot m==k-1 comes from fw (the cell
        // this group computed last step), committed into the cache here.
        const bool isF = (m == mf);
        const float a11 = isF ? fw11 : r11[c];
        const float a01 = isF ? fw01 : r01[c];
        const float a10 = isF ? fw10 : r10[c];
        r11[c] = a11; r01[c] = a01; r10[c] = a10;
        const bool on = lact && (m < mhi);
        if (on) {
            const float4 nxt = Q4[qjbc + i + m + 1];  // quad(q+1, j); imm offset
            const float base = a11 + nxt.z;           // s11[i][q] + s01[q+1][j]
            const float p01v = a01 + cur.x;           // s01[i][q] + s00[q][j]
            const float p11v = a10 + cur.y;           // s10[i][q] + s11[q][j]
            if (base > bmax) { bmax = base; ib = m; }  // strict > keeps earliest m
            if (p01v > v01) { v01 = p01v; i01 = m; }
            if (p11v > v11) { v11 = p11v; i11 = m; }
            cur = nxt;
        }
    }

    // Incremental prefetch of next step's operands (overlaps reduction+barrier).
    {
        const bool nact = i < kN - (k + 1);
        qjb += j + 1; ++j; pL += kN; ++pR;
        vL = nact ? *pL : 0.f;
        vR = nact ? *pR : 0.f;
    }

    // Value butterfly (pure DPP, VALU pipe only). P=4: 2 levels; P=8: 3.
    float gB = dppMax<0x4E>(dppMax<0xB1>(bmax));
    float g01 = dppMax<0x4E>(dppMax<0xB1>(v01));
    float g11 = dppMax<0x4E>(dppMax<0xB1>(v11));
    if constexpr (P == 8) {
        gB = dppMax<0x141>(gB); g01 = dppMax<0x141>(g01); g11 = dppMax<0x141>(g11);
    }
    // Earliest-m argmax: mask losers to INT_MAX, min-butterfly (pure DPP).
    int cB = (bmax == gB) ? ib : 0x7FFFFFFF;
    int c01 = (v01 == g01) ? i01 : 0x7FFFFFFF;
    int c11 = (v11 == g11) ? i11 : 0x7FFFFFFF;
    cB = dppMinI<0x4E>(dppMinI<0xB1>(cB));
    c01 = dppMinI<0x4E>(dppMinI<0xB1>(c01));
    c11 = dppMinI<0x4E>(dppMinI<0xB1>(c11));
    if constexpr (P == 8) {
        cB = dppMinI<0x141>(cB); c01 = dppMinI<0x141>(c01); c11 = dppMinI<0x141>(c11);
    }

    // All lanes hold the written-cell values -> fw for next step (m = k).
    // Identical arithmetic to writeCell => bitwise-equal values.
    const float v10f = (gB + vRc) + kArcBonus;
    const float new10 = (v10f > kThresh) ? v10f : kNeg;
    float v11m = g11;
    if (new10 > v11m) v11m = new10;
    fw11 = (v11m > kThresh) ? v11m : kNeg;  // w.y = s11(i,j)
    fw01 = (g01 > kThresh) ? g01 : kNeg;    // w.z = s01(i,j)
    fw10 = (v10f > kThresh) ? v10f : kNeg;  // w.w = s10(i,j)

    if (act && l == 0) {
        writeCell(Q4, wsBT, qjbc, i, rbi + k - 1, k,
                  gB, cB, vLc, vRc, g01, c01, g11, c11);
    }
}

// Phase driver: waveActive is monotone in k, so each wave runs compute-steps
// to its private kEnd, then a barrier-only loop (dead waves issue nothing).
template <int LP, int C>
__device__ __forceinline__ void runPhaseC(int k0, int k1, int tid,
        float4* __restrict__ Q4, uint32_t* __restrict__ wsBT,
        const float* __restrict__ v,
        float (&r11)[kCMax], float (&r01)[kCMax], float (&r10)[kCMax]) {
    const int i = tid >> LP;
    const int l = tid & ((1 << LP) - 1);
    const int firstGroup = (tid & ~63) >> LP;   // wave-uniform
    int kEnd = kN - firstGroup;                 // first k with whole wave dead
    if (kEnd > k1) kEnd = k1;
    if (kEnd > k0) {
        int j = i + k0;
        int qjb = colBaseD(j);
        const int rbi = rowBase(i & (kN - 1));
        const float* pL = v + (size_t)j * kN + i;
        const float* pR = v + (size_t)i * kN + j;
        const bool a0 = i < kN - k0;
        float vL = a0 ? *pL : 0.f;  // issue loads first: latency hides under preload
        float vR = a0 ? *pR : 0.f;
        preloadRow<LP, C>(k0, tid, Q4, r11, r01, r10);
        float fw11 = kNeg, fw01 = kNeg, fw10 = kNeg;
        fwInit<LP, C>(k0, tid, r11, r01, r10, fw11, fw01, fw10);
        for (int k = k0; k < kEnd; ++k) {
            doStepC<LP, C>(k, i, l, Q4, wsBT, j, qjb, rbi, pL, pR, vL, vR,
                           r11, r01, r10, fw11, fw01, fw10);
            ldsBarrier();
        }
        for (int k = kEnd; k < k1; ++k) ldsBarrier();
    } else {
        for (int k = k0; k < k1; ++k) ldsBarrier();
    }
}

__global__ __launch_bounds__(kThreads) void eisner_dp(
    const float* __restrict__ vinfo,  // [B][N][N] fp32
    float* __restrict__ outS,         // [B][N][N][2][2] fp32 scores
    float* __restrict__ outBT,        // [B][N][N][2][2] fp32 backtrace (integer-valued)
    uint32_t* __restrict__ btPacked)  // [B][kTri] packed backtrace bytes (d_ws)
{
    extern __shared__ float4 Q4[];

    const int tid = threadIdx.x;
    const int b = blockIdx.x;
    const float* v = vinfo + (size_t)b * kN * kN;
    uint32_t* wsBT = btPacked + (size_t)b * kTri;

    // Diagonal quads = 0. Off-diagonal cells need no init (written before read).
    const float4 zeroq = make_float4(0.f, 0.f, 0.f, 0.f);
    if (tid < kN) Q4[colBaseD(tid) + tid] = zeroq;
    __syncthreads();

    // ---- serial phase (k = 1..16): waves 0-1 compute, waves 2-7 barrier-only ----
    if ((tid & ~63) < kN - 1) {
        const int i = tid;
        float sr11[17], sr01[17], sr10[17];
        int j = i + 1;
        int qjb = colBaseD(j);
        const int rbi = rowBase(i & (kN - 1));
        const float* pL = v + (size_t)j * kN + i;
        const float* pR = v + (size_t)i * kN + j;
        const bool a0 = i < kN - 1;
        float vL = a0 ? *pL : 0.f;
        float vR = a0 ? *pR : 0.f;
#pragma unroll
        for (int k = 1; k <= 16; ++k) {
            doStepSerialReg(k, i, Q4, wsBT, j, qjb, rbi, pL, pR, vL, vR,
                            sr11, sr01, sr10);
            ldsBarrier();
        }
    } else {
#pragma unroll
        for (int k = 1; k <= 16; ++k) ldsBarrier();
    }

    // Row caches (registers); slots filled by preloadRow + fw commits.
    float r11[kCMax], r01[kCMax], r10[kCMax];
#pragma unroll
    for (int c = 0; c < kCMax; ++c) { r11[c] = kNeg; r01[c] = kNeg; r10[c] = kNeg; }

    // Phase table (P*C >= k1-1; groups = 512/P >= cells at k0):
    runPhaseC<2, 8>(17, 32, tid, Q4, wsBT, v, r11, r01, r10);    // P4: 4*8=32 >= 31
    runPhaseC<2, 12>(32, 48, tid, Q4, wsBT, v, r11, r01, r10);   // 4*12=48 >= 47
    runPhaseC<2, 16>(48, 64, tid, Q4, wsBT, v, r11, r01, r10);   // 4*16=64 >= 63
    runPhaseC<3, 12>(64, 96, tid, Q4, wsBT, v, r11, r01, r10);   // P8: 8*12=96 >= 95
    runPhaseC<3, 16>(96, 128, tid, Q4, wsBT, v, r11, r01, r10);  // 8*16=128 >= 127

    // Full barrier (drains vmcnt) before reading wsBT back.
    __syncthreads();

    // ---- epilogue: emit full [N][N][2][2] scores + backtrace, coalesced ----
    float4* gS4 = (float4*)(outS + (size_t)b * kN * kN * 4);
    float4* gB4 = (float4*)(outBT + (size_t)b * kN * kN * 4);
    const float4 negq = make_float4(kNeg, kNeg, kNeg, kNeg);
    for (int c = tid; c < kN * kN; c += kThreads) {
        const int i = c >> 7, j = c & (kN - 1);
        if (i < j) {
            const float4 q = Q4[colBaseD(j) + i];
            gS4[c] = make_float4(q.x, q.z, q.w, q.y);  // {s00, s01, s10, s11}
            const uint32_t p = wsBT[rowBase(i) + (j - i - 1)];
            gB4[c] = make_float4((float)(p & 255u), (float)((p >> 8) & 255u),
                                 (float)((p >> 16) & 255u), (float)(p >> 24));
        } else if (i == j) {
            gS4[c] = zeroq;
            gB4[c] = zeroq;
        } else {
            gS4[c] = negq;
            gB4[c] = zeroq;
        }
    }
}

extern "C" void kernel_launch(void* const* d_in, const int* in_sizes, int n_in,
                              void* d_out, int out_size, void* d_ws, size_t ws_size,
                              hipStream_t stream) {
    (void)n_in; (void)out_size; (void)ws_size;
    const float* vinfo = (const float*)d_in[0];  // fp32 [B][N][N]
    const int B = in_sizes[1];                   // b_buffer_size has B elements
    float* outS = (float*)d_out;
    float* outBT = outS + (size_t)B * kN * kN * 4;
    uint32_t* btPacked = (uint32_t*)d_ws;        // needs B*kTri*4 = ~2.1 MB

    hipFuncSetAttribute(reinterpret_cast<const void*>(eisner_dp),
                        hipFuncAttributeMaxDynamicSharedMemorySize, kDynLds);

    eisner_dp<<<dim3(B), dim3(kThreads), kDynLds, stream>>>(vinfo, outS, outBT, btPacked);
}

// Round 9
// 228.635 us; speedup vs baseline: 1.2357x; 1.2357x over previous
//
#include <hip/hip_runtime.h>
#include <stdint.h>
#include <utility>

static constexpr int kN = 128;
static constexpr int kTri = (kN * (kN - 1)) / 2;   // 8128 (BT scratch indexing)
static constexpr int kTriD = (kN * (kN + 1)) / 2;  // 8256 cells incl. diagonal
static constexpr int kThreads = 1024;              // 16 waves: TLP is needed (R8 lesson)
static constexpr float kNeg = -9999.0f;
static constexpr float kThresh = -9000.0f;
static constexpr float kArcBonus = 5.0f;
static constexpr int kDynLds = kTriD * 16;  // 132,096 B (one float4 quad per cell)
static constexpr int kCMax = 9;             // max row-cache slots per lane

__device__ __forceinline__ int rowBase(int i) { return (i * (2 * kN - 1 - i)) / 2; }
__device__ __forceinline__ int colBaseD(int c) { return (c * (c + 1)) / 2; }  // cells (r<=c, c)

// LDS-only workgroup barrier: orders LDS without draining vmcnt (wsBT stores
// and vL/vR prefetch loads stay in flight across steps).
__device__ __forceinline__ void ldsBarrier() {
    asm volatile("s_waitcnt lgkmcnt(0)\n\ts_barrier" ::: "memory");
}

// DPP cross-lane reduce helpers -- pure VALU, never touch the LDS pipe.
// 0xB1 xor1, 0x4E xor2, 0x141 half-mirror (8 lanes), 0x140 row-mirror (16).
template <int CTRL>
__device__ __forceinline__ float dppMax(float x) {
    const int y = __builtin_amdgcn_update_dpp(__float_as_int(x), __float_as_int(x),
                                              CTRL, 0xF, 0xF, true);
    return fmaxf(x, __int_as_float(y));
}
template <int CTRL>
__device__ __forceinline__ int dppMinI(int x) {
    const int y = __builtin_amdgcn_update_dpp(x, x, CTRL, 0xF, 0xF, true);
    return (y < x) ? y : x;
}

// Quad per cell: {x=s00, y=s11, z=s01, w=s10}, col-major incl. diagonal (diag=0).
__device__ __forceinline__ float4 writeCell(float4* __restrict__ Q4,
                                            uint32_t* __restrict__ wsBT,
                                            int qjb, int i, int wsIdx, int k,
                                            float gb, int ib, float vLc, float vRc,
                                            float v01, int i01, float v11, int i11) {
    const float v00 = (gb + vLc) + kArcBonus;
    const float v10 = (gb + vRc) + kArcBonus;
    const float new10 = (v10 > kThresh) ? v10 : kNeg;
    if (new10 > v11) { v11 = new10; i11 = k; }  // q=j candidate; strict > keeps earlier q
    float4 w = make_float4(kNeg, kNeg, kNeg, kNeg);
    uint32_t p = 0;
    if (v00 > kThresh) { w.x = v00; p |= (uint32_t)(i + ib); }
    if (v01 > kThresh) { w.z = v01; p |= (uint32_t)(i + i01) << 8; }
    if (v10 > kThresh) { w.w = v10; p |= (uint32_t)(i + ib) << 16; }
    if (v11 > kThresh) { w.y = v11; p |= (uint32_t)(i + i11) << 24; }
    Q4[qjb + i] = w;      // one ds_write_b128
    wsBT[wsIdx] = p;      // lone global store; drained at the final __syncthreads
    return w;
}

// Serial step (k<=16), k COMPILE-TIME (caller unrolled): one thread per cell,
// i = tid fixed, all row operands are this thread's own prior outputs mirrored
// in sr[] registers. Incremental j/qjb/pL/pR (no per-step remap).
__device__ __forceinline__ void doStepSerialReg(int k, int i,
                                                float4* __restrict__ Q4,
                                                uint32_t* __restrict__ wsBT,
                                                int& j, int& qjb, int rbi,
                                                const float*& pL, const float*& pR,
                                                float& vL, float& vR,
                                                float (&sr11)[17], float (&sr01)[17],
                                                float (&sr10)[17]) {
    const bool act = i < kN - k;
    const float vLc = vL, vRc = vR;
    const int qjbc = qjb;
    float bmax = -3.0e38f, v01 = -3.0e38f, v11 = -3.0e38f;
    int ib = 0, i01 = 0, i11 = 0x7FFFFFFF;
    if (act) {
        float4 cur = Q4[qjbc + i + 1];  // quad(i+1, j); diagonal zeros when k==1
        bmax = cur.z; ib = 0;           // base(0) = 0 + s01[i+1][j]
        const float p00 = (cur.z + vLc) + kArcBonus;
        v01 = (p00 > kThresh) ? p00 : kNeg; i01 = 0;  // part00 seed
#pragma unroll
        for (int m = 1; m < 16; ++m) {
            if (m < k) {  // compile-time when k is constant-folded
                const float4 nxt = Q4[qjbc + i + m + 1];  // quad(q+1, j)
                const float base = sr11[m] + nxt.z;       // s11[i][q] + s01[q+1][j]
                const float p01v = sr01[m] + cur.x;       // s01[i][q] + s00[q][j]
                const float p11v = sr10[m] + cur.y;       // s10[i][q] + s11[q][j]
                if (base > bmax) { bmax = base; ib = m; }  // strict > keeps earliest m
                if (p01v > v01) { v01 = p01v; i01 = m; }
                if (p11v > v11) { v11 = p11v; i11 = m; }
                cur = nxt;
            }
        }
    }
    // Incremental prefetch of next step's operands (overlaps write + barrier).
    if (k < 16) {
        const bool nact = i < kN - (k + 1);
        qjb += j + 1; ++j; pL += kN; ++pR;
        vL = nact ? *pL : 0.f;
        vR = nact ? *pR : 0.f;
    }
    if (act) {
        const float4 w = writeCell(Q4, wsBT, qjbc, i, rbi + k - 1, k,
                                   bmax, ib, vLc, vRc, v01, i01, v11, i11);
        sr11[k] = w.y; sr01[k] = w.z; sr10[k] = w.w;  // constant index (k unrolled)
    }
}

// ---- Chunked phases: register row-cache + fw forwarding, k COMPILE-TIME ----
template <int LP, int C>
__device__ __forceinline__ void preloadRow(int k0, int tid,
                                           const float4* __restrict__ Q4,
                                           float (&r11)[kCMax], float (&r01)[kCMax],
                                           float (&r10)[kCMax]) {
    const int i = tid >> LP;
    const int l = tid & ((1 << LP) - 1);
    const int mlo = l * C;
    const int mstart = mlo ? mlo : 1;
    const bool act = i < (kN - k0);
#pragma unroll
    for (int c = 0; c < C; ++c) {
        const int m = mstart + c;
        if (act && (m < mlo + C) && (m <= k0 - 1)) {
            const float4 d = Q4[colBaseD(i + m) + i];  // quad(i, i+m), immutable
            r11[c] = d.y; r01[c] = d.z; r10[c] = d.w;
        }
    }
    // Slots with m > k0-1 stay stale: committed from fw at step k=m+1 before read.
}

// One DP step, K and K0 COMPILE-TIME. The fresh slot m=K-1's owner lane
// LF=(K-1)/C and slot CF are constants: a single predicated register commit
// replaces the old per-element isF ternary machinery (6C -> ~4 instrs/step).
template <int LP, int C, int K, int K0>
__device__ __forceinline__ void doStepCU(int i, int l,
                                         float4* __restrict__ Q4,
                                         uint32_t* __restrict__ wsBT,
                                         int& j, int& qjb, int rbi,
                                         const float*& pL, const float*& pR,
                                         float& vL, float& vR,
                                         float (&r11)[kCMax], float (&r01)[kCMax],
                                         float (&r10)[kCMax],
                                         float& fw11, float& fw01, float& fw10) {
    constexpr int P = 1 << LP;
    static_assert(P <= 16, "reductions must stay pure-DPP");
    static_assert(P * C >= K, "chunk coverage");
    const bool act = i < kN - K;
    const float vLc = vL, vRc = vR;  // prefetch below overwrites vL/vR
    const int mlo = l * C;
    const int mstart = mlo ? mlo : 1;
    const int mhi = (mlo + C < K) ? (mlo + C) : K;
    const int qjbc = qjb;

    // Fresh-slot commit: cell (i, i+K-1) computed by THIS group last step lives
    // in fw (butterfly broadcast). Owner lane/slot are compile-time. At K==K0
    // the slot was preloaded from LDS instead (fw not yet valid).
    if constexpr (K > K0) {
        constexpr int LF = (K - 1) / C;      // >= 1 (K-1 >= 17 > C)
        constexpr int CF = (K - 1) - LF * C; // static index
        static_assert(LF >= 1 && LF < P && CF >= 0 && CF < C, "fresh slot");
        if (l == LF) { r11[CF] = fw11; r01[CF] = fw01; r10[CF] = fw10; }
    }

    float bmax = -3.0e38f, v01 = -3.0e38f, v11 = -3.0e38f;
    int ib = 0x7FFFFFFF, i01 = 0x7FFFFFFF, i11 = 0x7FFFFFFF;

    const bool lact = act && (mstart < mhi);
    float4 cur = make_float4(0.f, 0.f, 0.f, 0.f);
    if (lact) cur = Q4[qjbc + i + mstart];  // column seed quad(i+mstart, j)
    if (act && mlo == 0) {
        bmax = cur.z; ib = 0;  // base(0) = 0 + s01[i+1][j]
        const float p00 = (cur.z + vLc) + kArcBonus;
        v01 = (p00 > kThresh) ? p00 : kNeg; i01 = 0;  // part00 seed
    }
#pragma unroll
    for (int c = 0; c < C; ++c) {
        const int m = mstart + c;
        const bool on = lact && (m < mhi);
        if (on) {
            const float4 nxt = Q4[qjbc + i + m + 1];  // quad(q+1, j); imm offset
            const float base = r11[c] + nxt.z;        // s11[i][q] + s01[q+1][j]
            const float p01v = r01[c] + cur.x;        // s01[i][q] + s00[q][j]
            const float p11v = r10[c] + cur.y;        // s10[i][q] + s11[q][j]
            if (base > bmax) { bmax = base; ib = m; }  // strict > keeps earliest m
            if (p01v > v01) { v01 = p01v; i01 = m; }
            if (p11v > v11) { v11 = p11v; i11 = m; }
            cur = nxt;
        }
    }

    // Incremental prefetch of next step's operands (overlaps reduction+barrier).
    {
        const bool nact = i < kN - (K + 1);
        qjb += j + 1; ++j; pL += kN; ++pR;
        vL = nact ? *pL : 0.f;
        vR = nact ? *pR : 0.f;
    }

    // Value butterfly (pure DPP, VALU pipe only).
    float gB = dppMax<0x141>(dppMax<0x4E>(dppMax<0xB1>(bmax)));
    float g01 = dppMax<0x141>(dppMax<0x4E>(dppMax<0xB1>(v01)));
    float g11 = dppMax<0x141>(dppMax<0x4E>(dppMax<0xB1>(v11)));
    if constexpr (P == 16) {
        gB = dppMax<0x140>(gB); g01 = dppMax<0x140>(g01); g11 = dppMax<0x140>(g11);
    }
    // Earliest-m argmax: mask losers to INT_MAX, min-butterfly (pure DPP).
    int cB = (bmax == gB) ? ib : 0x7FFFFFFF;
    int c01 = (v01 == g01) ? i01 : 0x7FFFFFFF;
    int c11 = (v11 == g11) ? i11 : 0x7FFFFFFF;
    cB = dppMinI<0x141>(dppMinI<0x4E>(dppMinI<0xB1>(cB)));
    c01 = dppMinI<0x141>(dppMinI<0x4E>(dppMinI<0xB1>(c01)));
    c11 = dppMinI<0x141>(dppMinI<0x4E>(dppMinI<0xB1>(c11)));
    if constexpr (P == 16) {
        cB = dppMinI<0x140>(cB); c01 = dppMinI<0x140>(c01); c11 = dppMinI<0x140>(c11);
    }

    // All lanes hold the written-cell values -> fw for next step (m = K).
    // Identical arithmetic to writeCell => bitwise-equal values.
    const float v10f = (gB + vRc) + kArcBonus;
    const float new10 = (v10f > kThresh) ? v10f : kNeg;
    float v11m = g11;
    if (new10 > v11m) v11m = new10;
    fw11 = (v11m > kThresh) ? v11m : kNeg;  // w.y = s11(i,j)
    fw01 = (g01 > kThresh) ? g01 : kNeg;    // w.z = s01(i,j)
    fw10 = (v10f > kThresh) ? v10f : kNeg;  // w.w = s10(i,j)

    if (act && l == 0) {
        writeCell(Q4, wsBT, qjbc, i, rbi + K - 1, K,
                  gB, cB, vLc, vRc, g01, c01, g11, c11);
    }
}

// Fold-expression unrolled phase: every K is a compile-time constant.
template <int LP, int C, int K0, int... Ks>
__device__ __forceinline__ void runSteps(std::integer_sequence<int, Ks...>,
        int i, int l, int kEndWave,
        float4* __restrict__ Q4, uint32_t* __restrict__ wsBT,
        int& j, int& qjb, int rbi,
        const float*& pL, const float*& pR, float& vL, float& vR,
        float (&r11)[kCMax], float (&r01)[kCMax], float (&r10)[kCMax],
        float& fw11, float& fw01, float& fw10) {
    // For each step: wave-uniform liveness guard around the body; barrier always.
    ((
        (K0 + Ks < kEndWave
             ? doStepCU<LP, C, K0 + Ks, K0>(i, l, Q4, wsBT, j, qjb, rbi, pL, pR,
                                            vL, vR, r11, r01, r10, fw11, fw01, fw10)
             : (void)0),
        ldsBarrier()
    ), ...);
}

template <int LP, int C, int K0, int K1>
__device__ __forceinline__ void runPhaseU(int tid,
        float4* __restrict__ Q4, uint32_t* __restrict__ wsBT,
        const float* __restrict__ v,
        float (&r11)[kCMax], float (&r01)[kCMax], float (&r10)[kCMax]) {
    const int i = tid >> LP;
    const int l = tid & ((1 << LP) - 1);
    const int firstGroup = (tid & ~63) >> LP;   // wave-uniform
    int kEndWave = kN - firstGroup;             // first K with whole wave dead
    if (kEndWave > K1) kEndWave = K1;
    int j = i + K0;
    int qjb = colBaseD(j);
    const int rbi = rowBase(i & (kN - 1));
    const float* pL = v + (size_t)j * kN + i;
    const float* pR = v + (size_t)i * kN + j;
    const bool a0 = i < kN - K0;
    float vL = a0 ? *pL : 0.f;  // issue loads first: latency hides under preload
    float vR = a0 ? *pR : 0.f;
    if (kEndWave > K0) preloadRow<LP, C>(K0, tid, Q4, r11, r01, r10);
    float fw11 = kNeg, fw01 = kNeg, fw10 = kNeg;
    runSteps<LP, C, K0>(std::make_integer_sequence<int, K1 - K0>{},
                        i, l, kEndWave, Q4, wsBT, j, qjb, rbi, pL, pR, vL, vR,
                        r11, r01, r10, fw11, fw01, fw10);
}

__global__ __launch_bounds__(kThreads) void eisner_dp(
    const float* __restrict__ vinfo,  // [B][N][N] fp32
    float* __restrict__ outS,         // [B][N][N][2][2] fp32 scores
    float* __restrict__ outBT,        // [B][N][N][2][2] fp32 backtrace (integer-valued)
    uint32_t* __restrict__ btPacked)  // [B][kTri] packed backtrace bytes (d_ws)
{
    extern __shared__ float4 Q4[];

    const int tid = threadIdx.x;
    const int b = blockIdx.x;
    const float* v = vinfo + (size_t)b * kN * kN;
    uint32_t* wsBT = btPacked + (size_t)b * kTri;

    // Diagonal quads = 0. Off-diagonal cells need no init (written before read).
    const float4 zeroq = make_float4(0.f, 0.f, 0.f, 0.f);
    if (tid < kN) Q4[colBaseD(tid) + tid] = zeroq;
    __syncthreads();

    // ---- serial phase (k = 1..16), fully unrolled, incremental addressing ----
    {
        const int i = tid;
        float sr11[17], sr01[17], sr10[17];
        int j = i + 1;
        int qjb = colBaseD(j);
        const int rbi = rowBase(i & (kN - 1));
        const float* pL = v + (size_t)j * kN + i;
        const float* pR = v + (size_t)i * kN + j;
        const bool a0 = i < kN - 1;
        float vL = a0 ? *pL : 0.f;
        float vR = a0 ? *pR : 0.f;
#pragma unroll
        for (int k = 1; k <= 16; ++k) {
            doStepSerialReg(k, i, Q4, wsBT, j, qjb, rbi, pL, pR, vL, vR,
                            sr11, sr01, sr10);
            ldsBarrier();
        }
    }

    // Row caches (registers); slots filled by preloadRow + fw commits.
    float r11[kCMax], r01[kCMax], r10[kCMax];
#pragma unroll
    for (int c = 0; c < kCMax; ++c) { r11[c] = kNeg; r01[c] = kNeg; r10[c] = kNeg; }

    // Tight phase table: C sized to each phase's max k (P*C >= k1-1).
    runPhaseU<3, 3, 17, 24>(tid, Q4, wsBT, v, r11, r01, r10);   // 8*3=24 >= 23
    runPhaseU<3, 5, 24, 40>(tid, Q4, wsBT, v, r11, r01, r10);   // 8*5=40 >= 39
    runPhaseU<3, 7, 40, 56>(tid, Q4, wsBT, v, r11, r01, r10);   // 8*7=56 >= 55
    runPhaseU<3, 9, 56, 64>(tid, Q4, wsBT, v, r11, r01, r10);   // 8*9=72 >= 63
    runPhaseU<4, 5, 64, 80>(tid, Q4, wsBT, v, r11, r01, r10);   // 16*5=80 >= 79
    runPhaseU<4, 7, 80, 112>(tid, Q4, wsBT, v, r11, r01, r10);  // 16*7=112 >= 111
    runPhaseU<4, 9, 112, 128>(tid, Q4, wsBT, v, r11, r01, r10); // 16*9=144 >= 127

    // Full barrier (drains vmcnt) before reading wsBT back.
    __syncthreads();

    // ---- epilogue: emit full [N][N][2][2] scores + backtrace, coalesced ----
    float4* gS4 = (float4*)(outS + (size_t)b * kN * kN * 4);
    float4* gB4 = (float4*)(outBT + (size_t)b * kN * kN * 4);
    const float4 negq = make_float4(kNeg, kNeg, kNeg, kNeg);
    for (int c = tid; c < kN * kN; c += kThreads) {
        const int i = c >> 7, j = c & (kN - 1);
        if (i < j) {
            const float4 q = Q4[colBaseD(j) + i];
            gS4[c] = make_float4(q.x, q.z, q.w, q.y);  // {s00, s01, s10, s11}
            const uint32_t p = wsBT[rowBase(i) + (j - i - 1)];
            gB4[c] = make_float4((float)(p & 255u), (float)((p >> 8) & 255u),
                                 (float)((p >> 16) & 255u), (float)(p >> 24));
        } else if (i == j) {
            gS4[c] = zeroq;
            gB4[c] = zeroq;
        } else {
            gS4[c] = negq;
            gB4[c] = zeroq;
        }
    }
}

extern "C" void kernel_launch(void* const* d_in, const int* in_sizes, int n_in,
                              void* d_out, int out_size, void* d_ws, size_t ws_size,
                              hipStream_t stream) {
    (void)n_in; (void)out_size; (void)ws_size;
    const float* vinfo = (const float*)d_in[0];  // fp32 [B][N][N]
    const int B = in_sizes[1];                   // b_buffer_size has B elements
    float* outS = (float*)d_out;
    float* outBT = outS + (size_t)B * kN * kN * 4;
    uint32_t* btPacked = (uint32_t*)d_ws;        // needs B*kTri*4 = ~2.1 MB

    hipFuncSetAttribute(reinterpret_cast<const void*>(eisner_dp),
                        hipFuncAttributeMaxDynamicSharedMemorySize, kDynLds);

    eisner_dp<<<dim3(B), dim3(kThreads), kDynLds, stream>>>(vinfo, outS, outBT, btPacked);
}